// Round 1
// baseline (368.338 us; speedup 1.0000x reference)
//
#include <hip/hip_runtime.h>

#define PD 88      // sequences == W dim
#define TD 128     // time == T dim
#define I0 133     // layer0 input size
#define HID 24     // LSTM hidden
#define GD 96      // gates = 4*HID
#define CD 48      // channels = 2*HID
#define NH 4       // heads
#define HDIM 12    // head dim
#define KW 13      // neighborhood

__device__ __forceinline__ int imin(int a,int b){return a<b?a:b;}
__device__ __forceinline__ int imax(int a,int b){return a>b?a:b;}

// ---------- xg layer0: XG[dir][p][t][g] = sum_i x[t][p][i]*w[dir][g][i] + b_ih[g]+b_hh[g]
__global__ __launch_bounds__(192) void xg0_kernel(
    const float* __restrict__ x,
    const float* __restrict__ wf, const float* __restrict__ wb,
    const float* __restrict__ bif, const float* __restrict__ bhf,
    const float* __restrict__ bib, const float* __restrict__ bhb,
    float* __restrict__ xg) {
  __shared__ float xl[16*136];
  const int r0 = blockIdx.x * 16;          // rows are (p,t), p-major; 16 | 128 so same p
  const int p = r0 >> 7;
  const int t0 = r0 & 127;
  for (int idx = threadIdx.x; idx < 16*I0; idx += 192) {
    int r = idx / I0, i = idx - r*I0;
    xl[r*136 + i] = x[((size_t)(t0+r)*PD + p)*I0 + i];
  }
  __syncthreads();
  const int dir = threadIdx.x / GD;
  const int g = threadIdx.x - dir*GD;
  const float* w = (dir ? wb : wf) + (size_t)g*I0;
  const float bsum = dir ? (bib[g]+bhb[g]) : (bif[g]+bhf[g]);
  float acc[16];
#pragma unroll
  for (int r=0;r<16;r++) acc[r]=bsum;
  for (int i=0; i<132; i+=4) {
    float w0=w[i],w1=w[i+1],w2=w[i+2],w3=w[i+3];
#pragma unroll
    for (int r=0;r<16;r++) {
      float4 xv = *reinterpret_cast<const float4*>(&xl[r*136+i]);
      acc[r] += xv.x*w0 + xv.y*w1 + xv.z*w2 + xv.w*w3;
    }
  }
  {
    float wl=w[132];
#pragma unroll
    for (int r=0;r<16;r++) acc[r] += xl[r*136+132]*wl;
  }
  size_t ob = (((size_t)dir*PD + p)*TD + t0)*GD + g;
#pragma unroll
  for (int r=0;r<16;r++) xg[ob + (size_t)r*GD] = acc[r];
}

// ---------- xg layer1: input H0[p][t][48]
__global__ __launch_bounds__(192) void xg1_kernel(
    const float* __restrict__ h0,
    const float* __restrict__ wf, const float* __restrict__ wb,
    const float* __restrict__ bif, const float* __restrict__ bhf,
    const float* __restrict__ bib, const float* __restrict__ bhb,
    float* __restrict__ xg) {
  __shared__ float yl[16*CD];
  const int r0 = blockIdx.x * 16;
  const int p = r0 >> 7, t0 = r0 & 127;
  for (int idx = threadIdx.x; idx < 16*CD; idx += 192)
    yl[idx] = h0[(size_t)r0*CD + idx];
  __syncthreads();
  const int dir = threadIdx.x / GD;
  const int g = threadIdx.x - dir*GD;
  const float* w = (dir ? wb : wf) + (size_t)g*CD;
  const float bsum = dir ? (bib[g]+bhb[g]) : (bif[g]+bhf[g]);
  float acc[16];
#pragma unroll
  for (int r=0;r<16;r++) acc[r]=bsum;
  for (int i=0;i<CD;i+=4) {
    float4 w4 = *reinterpret_cast<const float4*>(w+i);
#pragma unroll
    for (int r=0;r<16;r++) {
      float4 xv = *reinterpret_cast<const float4*>(&yl[r*CD+i]);
      acc[r] += xv.x*w4.x+xv.y*w4.y+xv.z*w4.z+xv.w*w4.w;
    }
  }
  size_t ob = (((size_t)dir*PD + p)*TD + t0)*GD + g;
#pragma unroll
  for (int r=0;r<16;r++) xg[ob + (size_t)r*GD] = acc[r];
}

// ---------- bidirectional LSTM recurrence: one block per sequence p, 192 threads = (dir, gate)
// mode 0: out[p][t][dir*24+j]   mode 1: out[t][p][dir*24+j]
__global__ __launch_bounds__(192) void lstm_kernel(
    const float* __restrict__ xg,
    const float* __restrict__ whf, const float* __restrict__ whb,
    float* __restrict__ out, const int mode) {
  const int p = blockIdx.x;
  const int dir = threadIdx.x / GD;
  const int g = threadIdx.x - dir*GD;
  const float* wh = (dir ? whb : whf) + (size_t)g*HID;
  float w[HID];
#pragma unroll
  for (int j=0;j<HID;j++) w[j]=wh[j];
  __shared__ float hl[2][HID];
  __shared__ float ga[2][GD];
  if (g < HID) hl[dir][g] = 0.f;
  float c = 0.f;
  const bool isg = (g>=2*HID && g<3*HID);   // tanh gate; others sigmoid
  const float sa = isg?2.f:1.f, sb = isg?-1.f:0.f, ss = isg?2.f:1.f;
  const float* xp = xg + ((size_t)dir*PD + p)*TD*GD;
  __syncthreads();
  int t = dir ? (TD-1) : 0;
  const int dt = dir ? -1 : 1;
  float nxt = xp[(size_t)t*GD + g];
  for (int s=0; s<TD; ++s) {
    float cur = nxt;
    if (s+1 < TD) nxt = xp[(size_t)(t+dt)*GD + g];   // prefetch next step
    float a0=0.f,a1=0.f,a2=0.f,a3=0.f;
#pragma unroll
    for (int j=0;j<HID;j+=4) {
      a0 += w[j]  *hl[dir][j];
      a1 += w[j+1]*hl[dir][j+1];
      a2 += w[j+2]*hl[dir][j+2];
      a3 += w[j+3]*hl[dir][j+3];
    }
    float acc = cur + ((a0+a1)+(a2+a3));
    // sigmoid for i,f,o; tanh(x)=2*sigmoid(2x)-1 for g
    ga[dir][g] = sa/(1.f+__expf(-ss*acc)) + sb;
    __syncthreads();
    if (g < HID) {
      float gi = ga[dir][g], gf = ga[dir][HID+g], gg = ga[dir][2*HID+g], go = ga[dir][3*HID+g];
      c = gf*c + gi*gg;
      float th = 2.f/(1.f+__expf(-2.f*c)) - 1.f;
      float h = go*th;
      hl[dir][g] = h;
      if (mode==0) out[((size_t)p*TD + t)*CD + dir*HID + g] = h;
      else         out[((size_t)t*PD + p)*CD + dir*HID + g] = h;
    }
    __syncthreads();
    t += dt;
  }
}

// ---------- qkv projection (rows of Y[t][w][48]); q pre-scaled by hd^-0.5
__global__ __launch_bounds__(192) void qkv_kernel(
    const float* __restrict__ y, const float* __restrict__ wq,
    const float* __restrict__ bq,
    float* __restrict__ Qb, float* __restrict__ Kb, float* __restrict__ Vb) {
  __shared__ float yl[16*CD];
  const int r0 = blockIdx.x*16;
  for (int idx=threadIdx.x; idx<16*CD; idx+=192)
    yl[idx] = y[(size_t)r0*CD + idx];
  __syncthreads();
  const int n = threadIdx.x;
  if (n >= 3*CD) return;
  const float* w = wq + (size_t)n*CD;
  float b = bq[n];
  float acc[16];
#pragma unroll
  for (int r=0;r<16;r++) acc[r]=b;
  for (int i=0;i<CD;i+=4) {
    float4 w4 = *reinterpret_cast<const float4*>(w+i);
#pragma unroll
    for (int r=0;r<16;r++) {
      float4 xv = *reinterpret_cast<const float4*>(&yl[r*CD+i]);
      acc[r] += xv.x*w4.x+xv.y*w4.y+xv.z*w4.z+xv.w*w4.w;
    }
  }
  float* dst; int col; float scale = 1.f;
  if (n < CD)        { dst = Qb; col = n;      scale = 0.28867513459481287f; }
  else if (n < 2*CD) { dst = Kb; col = n-CD; }
  else               { dst = Vb; col = n-2*CD; }
#pragma unroll
  for (int r=0;r<16;r++) dst[(size_t)(r0+r)*CD + col] = acc[r]*scale;
}

// ---------- NATTEN 2D: 8x8 pixel tile, 4 heads, K/V halo (20x20) staged in LDS
__global__ __launch_bounds__(256) void natten_kernel(
    const float* __restrict__ Qb, const float* __restrict__ Kb,
    const float* __restrict__ Vb, const float* __restrict__ rpb,
    float* __restrict__ out) {
  __shared__ float kl[NH*400*HDIM];   // [h][pos=lw*20+lt][12]
  __shared__ float vl[NH*400*HDIM];
  const int tb = blockIdx.x & 15;
  const int wb = blockIdx.x >> 4;     // 0..10
  const int t0 = tb*8, w0 = wb*8;
  const int ht0 = imin(imax(t0-6,0), TD-KW);
  const int hw0 = imin(imax(w0-6,0), PD-KW);
  for (int idx = threadIdx.x; idx < 400*HDIM; idx += 256) {
    int pos = idx / HDIM;
    int c4  = idx - pos*HDIM;         // float4 chunk 0..11 over 48 channels
    int lw = pos / 20, lt = pos - lw*20;
    int gt = imin(ht0+lt, TD-1), gw = imin(hw0+lw, PD-1);  // clamp (pads unused slots)
    int h = c4 / 3, j = c4 - h*3;
    size_t ga = ((size_t)gt*PD + gw)*CD + c4*4;
    *reinterpret_cast<float4*>(&kl[((size_t)h*400+pos)*HDIM + j*4]) =
        *reinterpret_cast<const float4*>(Kb + ga);
    *reinterpret_cast<float4*>(&vl[((size_t)h*400+pos)*HDIM + j*4]) =
        *reinterpret_cast<const float4*>(Vb + ga);
  }
  __syncthreads();
  const int head = threadIdx.x >> 6;  // wave per head
  const int pix  = threadIdx.x & 63;
  const int pt = pix >> 3, pw = pix & 7;
  const int t = t0+pt, w = w0+pw;
  const int ts = imin(imax(t-6,0), TD-KW);
  const int wsb = imin(imax(w-6,0), PD-KW);
  const int lt0 = ts - ht0, lw0 = wsb - hw0;
  const float* qp = Qb + ((size_t)t*PD + w)*CD + head*HDIM;
  float4 q0 = *reinterpret_cast<const float4*>(qp);
  float4 q1 = *reinterpret_cast<const float4*>(qp+4);
  float4 q2 = *reinterpret_cast<const float4*>(qp+8);
  const float* kb = kl + (size_t)head*4800;
  const float* vb = vl + (size_t)head*4800;
  const float* bb = rpb + head*625 + (ts-t+12)*25 + (wsb-w+12);
  float sum=0.f;
  float o0x=0,o0y=0,o0z=0,o0w=0, o1x=0,o1y=0,o1z=0,o1w=0, o2x=0,o2y=0,o2z=0,o2w=0;
  for (int pp=0; pp<KW; ++pp) {
    const int ltp = lt0+pp;
    const float* br = bb + pp*25;
    for (int qq=0; qq<KW; ++qq) {
      const int pos = (lw0+qq)*20 + ltp;
      const float* kr = kb + pos*HDIM;
      float4 k0=*reinterpret_cast<const float4*>(kr);
      float4 k1=*reinterpret_cast<const float4*>(kr+4);
      float4 k2=*reinterpret_cast<const float4*>(kr+8);
      float lg = br[qq];
      lg += q0.x*k0.x + q0.y*k0.y + q0.z*k0.z + q0.w*k0.w;
      lg += q1.x*k1.x + q1.y*k1.y + q1.z*k1.z + q1.w*k1.w;
      lg += q2.x*k2.x + q2.y*k2.y + q2.z*k2.z + q2.w*k2.w;
      float e = __expf(lg);           // logits are O(0.1..1): no max-sub needed
      sum += e;
      const float* vr = vb + pos*HDIM;
      float4 v0=*reinterpret_cast<const float4*>(vr);
      float4 v1=*reinterpret_cast<const float4*>(vr+4);
      float4 v2=*reinterpret_cast<const float4*>(vr+8);
      o0x += e*v0.x; o0y += e*v0.y; o0z += e*v0.z; o0w += e*v0.w;
      o1x += e*v1.x; o1y += e*v1.y; o1z += e*v1.z; o1w += e*v1.w;
      o2x += e*v2.x; o2y += e*v2.y; o2z += e*v2.z; o2w += e*v2.w;
    }
  }
  float inv = 1.f/sum;
  float* op = out + ((size_t)t*PD + w)*CD + head*HDIM;
  float4 r0v = {o0x*inv,o0y*inv,o0z*inv,o0w*inv};
  float4 r1v = {o1x*inv,o1y*inv,o1z*inv,o1w*inv};
  float4 r2v = {o2x*inv,o2y*inv,o2z*inv,o2w*inv};
  *reinterpret_cast<float4*>(op)   = r0v;
  *reinterpret_cast<float4*>(op+4) = r1v;
  *reinterpret_cast<float4*>(op+8) = r2v;
}

// ---------- output projection
__global__ __launch_bounds__(192) void proj_kernel(
    const float* __restrict__ ain, const float* __restrict__ wp,
    const float* __restrict__ bp, float* __restrict__ out) {
  __shared__ float al[16*CD];
  const int r0 = blockIdx.x*16;
  for (int idx=threadIdx.x; idx<16*CD; idx+=192)
    al[idx] = ain[(size_t)r0*CD + idx];
  __syncthreads();
  const int rs = threadIdx.x / CD;   // 0..3
  const int n  = threadIdx.x - rs*CD;
  const float* w = wp + (size_t)n*CD;
  float acc[4] = {0.f,0.f,0.f,0.f};
  for (int i=0;i<CD;i+=4) {
    float4 w4 = *reinterpret_cast<const float4*>(w+i);
#pragma unroll
    for (int k=0;k<4;k++) {
      float4 xv = *reinterpret_cast<const float4*>(&al[(rs+4*k)*CD+i]);
      acc[k] += xv.x*w4.x+xv.y*w4.y+xv.z*w4.z+xv.w*w4.w;
    }
  }
  float b = bp[n];
#pragma unroll
  for (int k=0;k<4;k++) out[(size_t)(r0+rs+4*k)*CD + n] = acc[k]+b;
}

extern "C" void kernel_launch(void* const* d_in, const int* in_sizes, int n_in,
                              void* d_out, int out_size, void* d_ws, size_t ws_size,
                              hipStream_t stream) {
  (void)in_sizes; (void)n_in; (void)out_size; (void)ws_size;
  const float* x        = (const float*)d_in[0];
  const float* w_ih_l0  = (const float*)d_in[1];
  const float* w_hh_l0  = (const float*)d_in[2];
  const float* b_ih_l0  = (const float*)d_in[3];
  const float* b_hh_l0  = (const float*)d_in[4];
  const float* w_ih_l0r = (const float*)d_in[5];
  const float* w_hh_l0r = (const float*)d_in[6];
  const float* b_ih_l0r = (const float*)d_in[7];
  const float* b_hh_l0r = (const float*)d_in[8];
  const float* w_ih_l1  = (const float*)d_in[9];
  const float* w_hh_l1  = (const float*)d_in[10];
  const float* b_ih_l1  = (const float*)d_in[11];
  const float* b_hh_l1  = (const float*)d_in[12];
  const float* w_ih_l1r = (const float*)d_in[13];
  const float* w_hh_l1r = (const float*)d_in[14];
  const float* b_ih_l1r = (const float*)d_in[15];
  const float* b_hh_l1r = (const float*)d_in[16];
  const float* w_qkv    = (const float*)d_in[17];
  const float* b_qkv    = (const float*)d_in[18];
  const float* rpb      = (const float*)d_in[19];
  const float* w_proj   = (const float*)d_in[20];
  const float* b_proj   = (const float*)d_in[21];
  float* out = (float*)d_out;

  float* ws = (float*)d_ws;
  const size_t NPIX = (size_t)TD*PD;          // 11264
  float* XG = ws;                              // 2*88*128*96 = 2,162,688 floats
  float* H0 = XG + (size_t)2*PD*TD*GD;
  float* Y  = H0 + NPIX*CD;
  float* Qb = Y  + NPIX*CD;
  float* Kb = Qb + NPIX*CD;
  float* Vb = Kb + NPIX*CD;
  float* AO = Vb + NPIX*CD;

  const int NROWB = (int)(NPIX/16);            // 704

  xg0_kernel<<<NROWB,192,0,stream>>>(x, w_ih_l0, w_ih_l0r, b_ih_l0, b_hh_l0, b_ih_l0r, b_hh_l0r, XG);
  lstm_kernel<<<PD,192,0,stream>>>(XG, w_hh_l0, w_hh_l0r, H0, 0);
  xg1_kernel<<<NROWB,192,0,stream>>>(H0, w_ih_l1, w_ih_l1r, b_ih_l1, b_hh_l1, b_ih_l1r, b_hh_l1r, XG);
  lstm_kernel<<<PD,192,0,stream>>>(XG, w_hh_l1, w_hh_l1r, Y, 1);

  for (int l=0; l<2; ++l) {
    qkv_kernel<<<NROWB,192,0,stream>>>(Y, w_qkv, b_qkv, Qb, Kb, Vb);
    natten_kernel<<<176,256,0,stream>>>(Qb, Kb, Vb, rpb, AO);
    proj_kernel<<<NROWB,192,0,stream>>>(AO, w_proj, b_proj, (l==1)? out : Y);
  }
}